// Round 6
// baseline (1090.677 us; speedup 1.0000x reference)
//
#include <hip/hip_runtime.h>
#include <hip/hip_cooperative_groups.h>
#include <hip/hip_bf16.h>
#include <hip/hip_fp16.h>
#include <math.h>

namespace cg = cooperative_groups;

#define HID 64

#if defined(__has_builtin)
#if __has_builtin(__builtin_amdgcn_cvt_pk_f32_fp8) && __has_builtin(__builtin_amdgcn_cvt_pk_fp8_f32)
#define HWFP8 1
#endif
#endif

typedef float vfloat2 __attribute__((ext_vector_type(2)));

// ---------------- helpers ----------------

__device__ __forceinline__ unsigned short f2bf(float x) {
    unsigned int u = __float_as_uint(x);
    unsigned int r = u + 0x7fffu + ((u >> 16) & 1u);   // RNE
    return (unsigned short)(r >> 16);
}

#ifndef HWFP8
__device__ __forceinline__ unsigned int enc8_sw(float a) {
    unsigned short hb = __half_as_ushort(__float2half(a));
    unsigned int r = (unsigned int)hb + 0x7fu + ((hb >> 8) & 1u);
    return (r >> 8) & 0xffu;
}
__device__ __forceinline__ float dec8_sw(unsigned int b) {
    return __half2float(__ushort_as_half((unsigned short)(b << 8)));
}
#endif

__device__ __forceinline__ unsigned int enc4(float a, float b, float c, float d) {
#ifdef HWFP8
    int r = __builtin_amdgcn_cvt_pk_fp8_f32(a, b, 0, false);
    r = __builtin_amdgcn_cvt_pk_fp8_f32(c, d, r, true);
    return (unsigned int)r;
#else
    return enc8_sw(a) | (enc8_sw(b) << 8) | (enc8_sw(c) << 16) | (enc8_sw(d) << 24);
#endif
}

__device__ __forceinline__ void dec4(unsigned int w, float* f) {
#ifdef HWFP8
    vfloat2 a = __builtin_amdgcn_cvt_pk_f32_fp8((int)w, false);
    vfloat2 b = __builtin_amdgcn_cvt_pk_f32_fp8((int)w, true);
    f[0] = a.x; f[1] = a.y; f[2] = b.x; f[3] = b.y;
#else
    f[0] = dec8_sw(w & 0xffu); f[1] = dec8_sw((w >> 8) & 0xffu);
    f[2] = dec8_sw((w >> 16) & 0xffu); f[3] = dec8_sw(w >> 24);
#endif
}

__device__ __forceinline__ void dec8(uint2 g, float* f) {
    dec4(g.x, f);
    dec4(g.y, f + 4);
}

// ================= MEGA cooperative kernel =================

struct MegaArgs {
    const float* x;
    const int* esrc; const int* edst;
    const int* prow; const int* pcol;
    const float* W1; const float* b1;
    const float* W2; const float* b2;
    const float* W3; const float* b3;
    const float* fcW; const float* fcb;
    const float* l1W; const float* l1b;
    const float* l2W; const float* l2b;
    float* out;
    int* deg; float* dinv; int* rowoff; int* fill;
    int* ccnt; int* coff; int* cfill; int* crow;
    float* hpoolT; float* hpre;
    int* ssrc; float* snorm;
    unsigned int* Yq; unsigned short* X1; unsigned short* X2;
    float* sArr;
    int N, E, P, NC, HFC, NCLS, rows, bs;
};

// single-block exclusive scan (run by one designated block)
__device__ void scan_block(const int* __restrict__ cnt, int* __restrict__ off, int n, int* part) {
    int t = threadIdx.x;
    int CH = (n + 255) >> 8;
    int lo = min(t * CH, n), hi = min(lo + CH, n);
    int sum = 0;
    for (int i = lo; i < hi; ++i) sum += cnt[i];
    part[t] = sum;
    __syncthreads();
    for (int o = 1; o < 256; o <<= 1) {
        int v = (t >= o) ? part[t - o] : 0;
        __syncthreads();
        part[t] += v;
        __syncthreads();
    }
    int run = (t == 0) ? 0 : part[t - 1];
    for (int i = lo; i < hi; ++i) { off[i] = run; run += cnt[i]; }
    if (t == 255) off[n] = run;
}

// grid-stride register-tiled GEMM; W read from global (16 KB, L1-resident broadcast).
// MODE 0: X fp32 [b,n,k] (row = n*8+b); MODE 1: X bf16 [row,k]. Output fp8 *S.
template<int MODE>
__device__ void gemm_stage(const void* __restrict__ Xv, const float* __restrict__ W,
                           unsigned int* __restrict__ Yq, float S,
                           int N, int rowsTot, float* sXT) {
    int t = threadIdx.x;
    int ci = t & 15, ri = t >> 4;
    int nT = (rowsTot + 63) >> 6;
    for (int tile = blockIdx.x; tile < nT; tile += gridDim.x) {
        __syncthreads();                       // protect sXT vs previous iteration
        int r0 = tile << 6;
        {
            int row = t & 63;
            int kg = t >> 6;
            int gr = r0 + row;
            bool ok = gr < rowsTot;
            const float* Xf = (const float*)Xv;
            const unsigned short* Xh = (const unsigned short*)Xv;
#pragma unroll
            for (int i = 0; i < 4; ++i) {
                int k = (kg + i * 4) * 4;
                float4 v = make_float4(0.f, 0.f, 0.f, 0.f);
                if (ok) {
                    if (MODE == 0) {
                        int n = gr >> 3, b = gr & 7;
                        v = *(const float4*)&Xf[((size_t)b * N + n) * 64 + k];
                    } else {
                        ushort4 u = *(const ushort4*)&Xh[(size_t)gr * 64 + k];
                        v.x = __uint_as_float(((unsigned int)u.x) << 16);
                        v.y = __uint_as_float(((unsigned int)u.y) << 16);
                        v.z = __uint_as_float(((unsigned int)u.z) << 16);
                        v.w = __uint_as_float(((unsigned int)u.w) << 16);
                    }
                }
                sXT[(k + 0) * 68 + row] = v.x;
                sXT[(k + 1) * 68 + row] = v.y;
                sXT[(k + 2) * 68 + row] = v.z;
                sXT[(k + 3) * 68 + row] = v.w;
            }
        }
        __syncthreads();
        float acc[4][4] = {};
#pragma unroll 16
        for (int k = 0; k < 64; ++k) {
            float4 xr = *(const float4*)&sXT[k * 68 + ri * 4];
            float4 wc = *(const float4*)&W[k * 64 + ci * 4];
            acc[0][0] = fmaf(xr.x, wc.x, acc[0][0]); acc[0][1] = fmaf(xr.x, wc.y, acc[0][1]);
            acc[0][2] = fmaf(xr.x, wc.z, acc[0][2]); acc[0][3] = fmaf(xr.x, wc.w, acc[0][3]);
            acc[1][0] = fmaf(xr.y, wc.x, acc[1][0]); acc[1][1] = fmaf(xr.y, wc.y, acc[1][1]);
            acc[1][2] = fmaf(xr.y, wc.z, acc[1][2]); acc[1][3] = fmaf(xr.y, wc.w, acc[1][3]);
            acc[2][0] = fmaf(xr.z, wc.x, acc[2][0]); acc[2][1] = fmaf(xr.z, wc.y, acc[2][1]);
            acc[2][2] = fmaf(xr.z, wc.z, acc[2][2]); acc[2][3] = fmaf(xr.z, wc.w, acc[2][3]);
            acc[3][0] = fmaf(xr.w, wc.x, acc[3][0]); acc[3][1] = fmaf(xr.w, wc.y, acc[3][1]);
            acc[3][2] = fmaf(xr.w, wc.z, acc[3][2]); acc[3][3] = fmaf(xr.w, wc.w, acc[3][3]);
        }
#pragma unroll
        for (int j = 0; j < 4; ++j) {
            int row = r0 + ri * 4 + j;
            if (row < rowsTot)
                Yq[(size_t)row * 16 + ci] =
                    enc4(acc[j][0] * S, acc[j][1] * S, acc[j][2] * S, acc[j][3] * S);
        }
    }
}

// grid-stride aggregation; 4 nodes per block (1 wave each), 8-deep edge pipeline.
template<int LAYER, bool STORE>
__device__ void agg_stage(const uint2* __restrict__ Y, const int* __restrict__ rowoff,
                          const int* __restrict__ ssrc, const float* __restrict__ snorm,
                          const float* __restrict__ dinv, const float* __restrict__ bias,
                          const float* __restrict__ fcW, uint4* __restrict__ O,
                          float* __restrict__ sArr, float invS, int N) {
    int wave = threadIdx.x >> 6, lane = threadIdx.x & 63;
    int hb = (lane & 7) * 8;
    float bv[8], wv[8];
#pragma unroll
    for (int k = 0; k < 8; ++k) { bv[k] = bias[hb + k]; wv[k] = fcW[3 * (hb + k) + LAYER]; }
    int nQ = (N + 3) >> 2;
    for (int q = blockIdx.x; q < nQ; q += gridDim.x) {
        int n = q * 4 + wave;
        if (n < N) {
            float dn = dinv[n];
            float w0 = dn * dn;
            float acc[8], f[8];
            dec8(Y[(size_t)n * 64 + lane], f);
#pragma unroll
            for (int k = 0; k < 8; ++k) acc[k] = w0 * f[k];

            int beg = rowoff[n], end = rowoff[n + 1];
            int i = beg;
            for (; i + 7 < end; i += 8) {
                int   sI[8];
                float wI[8];
                uint2 g[8];
#pragma unroll
                for (int u = 0; u < 8; ++u) { sI[u] = ssrc[i + u]; wI[u] = snorm[i + u]; }
#pragma unroll
                for (int u = 0; u < 8; ++u) g[u] = Y[(size_t)sI[u] * 64 + lane];
#pragma unroll
                for (int u = 0; u < 8; ++u) {
                    dec8(g[u], f);
#pragma unroll
                    for (int k = 0; k < 8; ++k) acc[k] = fmaf(wI[u], f[k], acc[k]);
                }
            }
            for (; i < end; ++i) {
                int s = ssrc[i];
                float w = snorm[i];
                dec8(Y[(size_t)s * 64 + lane], f);
#pragma unroll
                for (int k = 0; k < 8; ++k) acc[k] = fmaf(w, f[k], acc[k]);
            }

            float sv = 0.f;
#pragma unroll
            for (int k = 0; k < 8; ++k) {
                float o = fmaxf(fmaf(acc[k], invS, bv[k]), 0.f);
                acc[k] = o;
                sv = fmaf(o, wv[k], sv);
            }
            if (STORE) {
                uint4 o;
                o.x = (unsigned int)f2bf(acc[0]) | ((unsigned int)f2bf(acc[1]) << 16);
                o.y = (unsigned int)f2bf(acc[2]) | ((unsigned int)f2bf(acc[3]) << 16);
                o.z = (unsigned int)f2bf(acc[4]) | ((unsigned int)f2bf(acc[5]) << 16);
                o.w = (unsigned int)f2bf(acc[6]) | ((unsigned int)f2bf(acc[7]) << 16);
                O[(size_t)n * 64 + lane] = o;
            }
            sv += __shfl_down(sv, 4, 64);
            sv += __shfl_down(sv, 2, 64);
            sv += __shfl_down(sv, 1, 64);
            if ((lane & 7) == 0) {
                int b = lane >> 3;
                float* sp = sArr + (size_t)n * 8 + b;
                if (LAYER == 0) *sp = sv;
                else            *sp += sv;
            }
        }
    }
}

__global__ __launch_bounds__(256, 4) void k_mega(MegaArgs a) {
    cg::grid_group grid = cg::this_grid();
    __shared__ __align__(16) char smraw[64 * 68 * 4];   // 17408 B, unioned across stages
    float* sXT  = (float*)smraw;
    int*   sSc  = (int*)smraw;
    float* sHl  = (float*)smraw;
    float* sZ   = (float*)smraw;

    int t = threadIdx.x;
    int gth = blockIdx.x * blockDim.x + t;
    int GT = gridDim.x * blockDim.x;

    // ---- S0: zero workspace counters ----
    for (int i = gth; i < a.N; i += GT) { a.deg[i] = 0; a.fill[i] = 0; }
    for (int i = gth; i < a.NC; i += GT) { a.ccnt[i] = 0; a.cfill[i] = 0; }
    for (int i = gth; i < a.bs * a.HFC; i += GT) a.hpre[i] = 0.f;
    grid.sync();

    // ---- S1: degree / column counts ----
    for (int e = gth; e < a.E; e += GT) atomicAdd(&a.deg[a.edst[e]], 1);
    for (int p = gth; p < a.P; p += GT) atomicAdd(&a.ccnt[a.pcol[p]], 1);
    grid.sync();

    // ---- S2: dinv + scans (blocks 0 and 1) ----
    for (int i = gth; i < a.N; i += GT) a.dinv[i] = rsqrtf((float)(a.deg[i] + 1));
    if (blockIdx.x == 0)      scan_block(a.deg, a.rowoff, a.N, sSc);
    else if (blockIdx.x == 1) scan_block(a.ccnt, a.coff, a.NC, sSc);
    grid.sync();

    // ---- S3: scatter edge CSR + column CSR ----
    for (int e = gth; e < a.E; e += GT) {
        int s = a.esrc[e], d = a.edst[e];
        int pos = a.rowoff[d] + atomicAdd(&a.fill[d], 1);
        a.ssrc[pos] = s;
        a.snorm[pos] = a.dinv[s] * a.dinv[d];
    }
    for (int p = gth; p < a.P; p += GT) {
        int c = a.pcol[p];
        int pos = a.coff[c] + atomicAdd(&a.cfill[c], 1);
        a.crow[pos] = a.prow[p];
    }
    grid.sync();

    // ---- layers (fp8 message scales as round 5) ----
    const float S1v = 1.f, S2v = 16.f, S3v = 128.f;
    gemm_stage<0>(a.x, a.W1, a.Yq, S1v, a.N, a.rows, sXT);
    grid.sync();
    agg_stage<0, true>((const uint2*)a.Yq, a.rowoff, a.ssrc, a.snorm, a.dinv, a.b1, a.fcW,
                       (uint4*)a.X1, a.sArr, 1.f / S1v, a.N);
    grid.sync();
    gemm_stage<1>(a.X1, a.W2, a.Yq, S2v, a.N, a.rows, sXT);
    grid.sync();
    agg_stage<1, true>((const uint2*)a.Yq, a.rowoff, a.ssrc, a.snorm, a.dinv, a.b2, a.fcW,
                       (uint4*)a.X2, a.sArr, 1.f / S2v, a.N);
    grid.sync();
    gemm_stage<1>(a.X2, a.W3, a.Yq, S3v, a.N, a.rows, sXT);
    grid.sync();
    agg_stage<2, false>((const uint2*)a.Yq, a.rowoff, a.ssrc, a.snorm, a.dinv, a.b3, a.fcW,
                        nullptr, a.sArr, 1.f / S3v, a.N);
    grid.sync();

    // ---- pool: one wave per column ----
    {
        int lane = t & 63;
        int b = lane & 7;
        for (int c = blockIdx.x * 4 + (t >> 6); c < a.NC; c += gridDim.x * 4) {
            int beg = a.coff[c], end = a.coff[c + 1];
            float acc = 0.f;
            for (int i = beg + (lane >> 3); i < end; i += 8) {
                int r = a.crow[i];
                acc += a.sArr[(size_t)r * 8 + b];
            }
            acc += __shfl_down(acc, 32, 64);
            acc += __shfl_down(acc, 16, 64);
            acc += __shfl_down(acc, 8, 64);
            if (lane < 8) {
                float inv = 1.f / fmaxf((float)(end - beg), 1.f);
                a.hpoolT[(size_t)c * 8 + b] = acc * inv;
            }
        }
    }
    grid.sync();

    // ---- l1 partial GEMM: chunks of 16 columns ----
    {
        int nCh = (a.NC + 15) >> 4;
        float fcb0 = a.fcb[0];
        for (int cc = blockIdx.x; cc < nCh; cc += gridDim.x) {
            __syncthreads();
            if (t < 128) {
                int ci = t >> 3, b = t & 7;
                int c = cc * 16 + ci;
                sHl[ci * 8 + b] = (c < a.NC) ? (a.hpoolT[(size_t)c * 8 + b] + fcb0) : 0.f;
            }
            __syncthreads();
            int j = t & 127, bb = t >> 7;
            float ac0 = 0.f, ac1 = 0.f, ac2 = 0.f, ac3 = 0.f;
#pragma unroll
            for (int ci = 0; ci < 16; ++ci) {
                int c = cc * 16 + ci;
                float w = (c < a.NC) ? a.l1W[(size_t)c * a.HFC + j] : 0.f;
                ac0 = fmaf(sHl[ci * 8 + bb + 0], w, ac0);
                ac1 = fmaf(sHl[ci * 8 + bb + 2], w, ac1);
                ac2 = fmaf(sHl[ci * 8 + bb + 4], w, ac2);
                ac3 = fmaf(sHl[ci * 8 + bb + 6], w, ac3);
            }
            atomicAdd(&a.hpre[(size_t)(bb + 0) * a.HFC + j], ac0);
            atomicAdd(&a.hpre[(size_t)(bb + 2) * a.HFC + j], ac1);
            atomicAdd(&a.hpre[(size_t)(bb + 4) * a.HFC + j], ac2);
            atomicAdd(&a.hpre[(size_t)(bb + 6) * a.HFC + j], ac3);
        }
    }
    grid.sync();

    // ---- final: relu(l1) -> l2 -> log_softmax (block 0) ----
    if (blockIdx.x == 0) {
        int g = t >> 4, l16 = t & 15;
        int nout = a.bs * a.NCLS;
        float v = 0.f;
        int b = g / a.NCLS, k = g - b * a.NCLS;
        if (g < nout) {
            for (int j = l16; j < a.HFC; j += 16) {
                float h = fmaxf(a.hpre[(size_t)b * a.HFC + j] + a.l1b[j], 0.f);
                v = fmaf(h, a.l2W[(size_t)j * a.NCLS + k], v);
            }
        }
        v += __shfl_down(v, 8, 64);
        v += __shfl_down(v, 4, 64);
        v += __shfl_down(v, 2, 64);
        v += __shfl_down(v, 1, 64);
        __syncthreads();
        if (l16 == 0 && g < nout) sZ[g] = v + a.l2b[k];
        __syncthreads();
        if (t < a.bs) {
            float m = -1e30f;
            for (int c = 0; c < a.NCLS; ++c) m = fmaxf(m, sZ[t * a.NCLS + c]);
            float s = 0.f;
            for (int c = 0; c < a.NCLS; ++c) s += expf(sZ[t * a.NCLS + c] - m);
            float lse = m + logf(s);
            for (int c = 0; c < a.NCLS; ++c) a.out[t * a.NCLS + c] = sZ[t * a.NCLS + c] - lse;
        }
    }
}

// ================= fallback multi-kernel path (round-5) =================

__global__ void k_init_deg(int* __restrict__ deg, int N) {
    int i = blockIdx.x * blockDim.x + threadIdx.x;
    if (i < N) deg[i] = 1;
}
__global__ void k_count(const int* __restrict__ idx, int* __restrict__ cnt, int E) {
    int e = blockIdx.x * blockDim.x + threadIdx.x;
    if (e < E) atomicAdd(&cnt[idx[e]], 1);
}
__global__ void k_dinv(const int* __restrict__ deg, float* __restrict__ dinv, int N) {
    int i = blockIdx.x * blockDim.x + threadIdx.x;
    if (i < N) dinv[i] = rsqrtf((float)deg[i]);
}
template<int SUB>
__global__ void k_scan(const int* __restrict__ deg, int* __restrict__ rowoff, int N) {
    __shared__ int part[256];
    int t = threadIdx.x;
    int CH = (N + 255) >> 8;
    int lo = min(t * CH, N), hi = min(lo + CH, N);
    int sum = 0;
    for (int i = lo; i < hi; ++i) sum += deg[i] - SUB;
    part[t] = sum;
    __syncthreads();
    for (int off = 1; off < 256; off <<= 1) {
        int v = (t >= off) ? part[t - off] : 0;
        __syncthreads();
        part[t] += v;
        __syncthreads();
    }
    int run = (t == 0) ? 0 : part[t - 1];
    for (int i = lo; i < hi; ++i) { rowoff[i] = run; run += deg[i] - SUB; }
    if (t == 255) rowoff[N] = run;
}
__global__ void k_scatter_edges(const int* __restrict__ src, const int* __restrict__ dst,
                                const float* __restrict__ dinv, const int* __restrict__ rowoff,
                                int* __restrict__ fill, int* __restrict__ ssrc,
                                float* __restrict__ snorm, int E) {
    int e = blockIdx.x * blockDim.x + threadIdx.x;
    if (e >= E) return;
    int s = src[e], d = dst[e];
    int pos = rowoff[d] + atomicAdd(&fill[d], 1);
    ssrc[pos]  = s;
    snorm[pos] = dinv[s] * dinv[d];
}
__global__ void k_scatter_cols(const int* __restrict__ prow, const int* __restrict__ pcol,
                               const int* __restrict__ coff, int* __restrict__ cfill,
                               int* __restrict__ crow, int P) {
    int p = blockIdx.x * blockDim.x + threadIdx.x;
    if (p >= P) return;
    int c = pcol[p];
    int pos = coff[c] + atomicAdd(&cfill[c], 1);
    crow[pos] = prow[p];
}
template<int MODE>
__global__ __launch_bounds__(256) void k_gemm_rt(const void* __restrict__ Xv,
                                                 const float* __restrict__ W,
                                                 unsigned int* __restrict__ Yq,
                                                 float S, int N, int rowsTot) {
    __shared__ float sXT[64 * 68];
    int t = threadIdx.x;
    int r0 = blockIdx.x * 64;
    {
        int row = t & 63;
        int kg = t >> 6;
        int gr = r0 + row;
        bool ok = gr < rowsTot;
        const float* Xf = (const float*)Xv;
        const unsigned short* Xh = (const unsigned short*)Xv;
#pragma unroll
        for (int i = 0; i < 4; ++i) {
            int k = (kg + i * 4) * 4;
            float4 v = make_float4(0.f, 0.f, 0.f, 0.f);
            if (ok) {
                if (MODE == 0) {
                    int n = gr >> 3, b = gr & 7;
                    v = *(const float4*)&Xf[((size_t)b * N + n) * 64 + k];
                } else {
                    ushort4 u = *(const ushort4*)&Xh[(size_t)gr * 64 + k];
                    v.x = __uint_as_float(((unsigned int)u.x) << 16);
                    v.y = __uint_as_float(((unsigned int)u.y) << 16);
                    v.z = __uint_as_float(((unsigned int)u.z) << 16);
                    v.w = __uint_as_float(((unsigned int)u.w) << 16);
                }
            }
            sXT[(k + 0) * 68 + row] = v.x;
            sXT[(k + 1) * 68 + row] = v.y;
            sXT[(k + 2) * 68 + row] = v.z;
            sXT[(k + 3) * 68 + row] = v.w;
        }
    }
    __syncthreads();
    int ci = t & 15, ri = t >> 4;
    float acc[4][4] = {};
#pragma unroll 16
    for (int k = 0; k < 64; ++k) {
        float4 xr = *(const float4*)&sXT[k * 68 + ri * 4];
        float4 wc = *(const float4*)&W[k * 64 + ci * 4];
        acc[0][0] = fmaf(xr.x, wc.x, acc[0][0]); acc[0][1] = fmaf(xr.x, wc.y, acc[0][1]);
        acc[0][2] = fmaf(xr.x, wc.z, acc[0][2]); acc[0][3] = fmaf(xr.x, wc.w, acc[0][3]);
        acc[1][0] = fmaf(xr.y, wc.x, acc[1][0]); acc[1][1] = fmaf(xr.y, wc.y, acc[1][1]);
        acc[1][2] = fmaf(xr.y, wc.z, acc[1][2]); acc[1][3] = fmaf(xr.y, wc.w, acc[1][3]);
        acc[2][0] = fmaf(xr.z, wc.x, acc[2][0]); acc[2][1] = fmaf(xr.z, wc.y, acc[2][1]);
        acc[2][2] = fmaf(xr.z, wc.z, acc[2][2]); acc[2][3] = fmaf(xr.z, wc.w, acc[2][3]);
        acc[3][0] = fmaf(xr.w, wc.x, acc[3][0]); acc[3][1] = fmaf(xr.w, wc.y, acc[3][1]);
        acc[3][2] = fmaf(xr.w, wc.z, acc[3][2]); acc[3][3] = fmaf(xr.w, wc.w, acc[3][3]);
    }
#pragma unroll
    for (int j = 0; j < 4; ++j) {
        int row = r0 + ri * 4 + j;
        if (row < rowsTot)
            Yq[(size_t)row * 16 + ci] = enc4(acc[j][0] * S, acc[j][1] * S, acc[j][2] * S, acc[j][3] * S);
    }
}
template<int LAYER, bool STORE>
__global__ __launch_bounds__(256) void k_agg(const uint2* __restrict__ Y,
                                             const int* __restrict__ rowoff,
                                             const int* __restrict__ ssrc,
                                             const float* __restrict__ snorm,
                                             const float* __restrict__ dinv,
                                             const float* __restrict__ bias,
                                             const float* __restrict__ fcW,
                                             uint4* __restrict__ O,
                                             float* __restrict__ sArr,
                                             float invS, int N) {
    int n = blockIdx.x * 4 + (threadIdx.x >> 6);
    if (n >= N) return;
    int lane = threadIdx.x & 63;
    int hb = (lane & 7) * 8;
    float bv[8], wv[8];
#pragma unroll
    for (int k = 0; k < 8; ++k) { bv[k] = bias[hb + k]; wv[k] = fcW[3 * (hb + k) + LAYER]; }
    float dn = dinv[n];
    float w0 = dn * dn;
    float acc[8], f[8];
    dec8(Y[(size_t)n * 64 + lane], f);
#pragma unroll
    for (int k = 0; k < 8; ++k) acc[k] = w0 * f[k];
    int beg = rowoff[n], end = rowoff[n + 1];
    int i = beg;
    for (; i + 7 < end; i += 8) {
        int   sI[8];
        float wI[8];
        uint2 g[8];
#pragma unroll
        for (int u = 0; u < 8; ++u) { sI[u] = ssrc[i + u]; wI[u] = snorm[i + u]; }
#pragma unroll
        for (int u = 0; u < 8; ++u) g[u] = Y[(size_t)sI[u] * 64 + lane];
#pragma unroll
        for (int u = 0; u < 8; ++u) {
            dec8(g[u], f);
#pragma unroll
            for (int k = 0; k < 8; ++k) acc[k] = fmaf(wI[u], f[k], acc[k]);
        }
    }
    for (; i < end; ++i) {
        int s = ssrc[i];
        float w = snorm[i];
        dec8(Y[(size_t)s * 64 + lane], f);
#pragma unroll
        for (int k = 0; k < 8; ++k) acc[k] = fmaf(w, f[k], acc[k]);
    }
    float sv = 0.f;
#pragma unroll
    for (int k = 0; k < 8; ++k) {
        float o = fmaxf(fmaf(acc[k], invS, bv[k]), 0.f);
        acc[k] = o;
        sv = fmaf(o, wv[k], sv);
    }
    if (STORE) {
        uint4 o;
        o.x = (unsigned int)f2bf(acc[0]) | ((unsigned int)f2bf(acc[1]) << 16);
        o.y = (unsigned int)f2bf(acc[2]) | ((unsigned int)f2bf(acc[3]) << 16);
        o.z = (unsigned int)f2bf(acc[4]) | ((unsigned int)f2bf(acc[5]) << 16);
        o.w = (unsigned int)f2bf(acc[6]) | ((unsigned int)f2bf(acc[7]) << 16);
        O[(size_t)n * 64 + lane] = o;
    }
    sv += __shfl_down(sv, 4, 64);
    sv += __shfl_down(sv, 2, 64);
    sv += __shfl_down(sv, 1, 64);
    if ((lane & 7) == 0) {
        int b = lane >> 3;
        float* sp = sArr + (size_t)n * 8 + b;
        if (LAYER == 0) *sp = sv;
        else            *sp += sv;
    }
}
__global__ __launch_bounds__(64) void k_poolg(const float* __restrict__ sArr,
                                              const int* __restrict__ coff,
                                              const int* __restrict__ crow,
                                              float* __restrict__ hpoolT) {
    int c = blockIdx.x;
    int lane = threadIdx.x;
    int beg = coff[c], end = coff[c + 1];
    int b = lane & 7;
    float acc = 0.f;
    for (int i = beg + (lane >> 3); i < end; i += 8) {
        int r = crow[i];
        acc += sArr[(size_t)r * 8 + b];
    }
    acc += __shfl_down(acc, 32, 64);
    acc += __shfl_down(acc, 16, 64);
    acc += __shfl_down(acc, 8, 64);
    if (lane < 8) {
        float inv = 1.f / fmaxf((float)(end - beg), 1.f);
        hpoolT[(size_t)c * 8 + b] = acc * inv;
    }
}
__global__ __launch_bounds__(128) void k_l1p(const float* __restrict__ hpoolT,
                                             const float* __restrict__ fcb,
                                             const float* __restrict__ l1W,
                                             float* __restrict__ hpre,
                                             int NC, int HFC, int CHUNK) {
    __shared__ float hl[64];
    int b = blockIdx.y;
    int c0 = blockIdx.x * CHUNK;
    int j = threadIdx.x;
    int cend = min(c0 + CHUNK, NC);
    for (int c = c0 + j; c < cend; c += blockDim.x)
        hl[c - c0] = hpoolT[(size_t)c * 8 + b] + fcb[0];
    __syncthreads();
    float acc = 0.f;
    for (int c = c0; c < cend; ++c) acc = fmaf(hl[c - c0], l1W[(size_t)c * HFC + j], acc);
    atomicAdd(&hpre[(size_t)b * HFC + j], acc);
}
__global__ __launch_bounds__(256) void k_final(const float* __restrict__ hpre,
                                               const float* __restrict__ l1b,
                                               const float* __restrict__ l2W,
                                               const float* __restrict__ l2b,
                                               float* __restrict__ out,
                                               int bs, int HFC, int NCLS) {
    __shared__ float z[64];
    int t = threadIdx.x;
    int g = t >> 4, l16 = t & 15;
    int nout = bs * NCLS;
    float v = 0.f;
    int b = g / NCLS, k = g - b * NCLS;
    if (g < nout) {
        for (int j = l16; j < HFC; j += 16) {
            float h = fmaxf(hpre[(size_t)b * HFC + j] + l1b[j], 0.f);
            v = fmaf(h, l2W[(size_t)j * NCLS + k], v);
        }
    }
    v += __shfl_down(v, 8, 64);
    v += __shfl_down(v, 4, 64);
    v += __shfl_down(v, 2, 64);
    v += __shfl_down(v, 1, 64);
    if (l16 == 0 && g < nout) z[g] = v + l2b[k];
    __syncthreads();
    if (t < bs) {
        float m = -1e30f;
        for (int c = 0; c < NCLS; ++c) m = fmaxf(m, z[t * NCLS + c]);
        float s = 0.f;
        for (int c = 0; c < NCLS; ++c) s += expf(z[t * NCLS + c] - m);
        float lse = m + logf(s);
        for (int c = 0; c < NCLS; ++c) out[t * NCLS + c] = z[t * NCLS + c] - lse;
    }
}

// ---------------- launcher ----------------

extern "C" void kernel_launch(void* const* d_in, const int* in_sizes, int n_in,
                              void* d_out, int out_size, void* d_ws, size_t ws_size,
                              hipStream_t stream) {
    const float* x   = (const float*)d_in[0];
    const int* eidx  = (const int*)d_in[2];
    const int* prow  = (const int*)d_in[3];
    const int* pcol  = (const int*)d_in[4];
    const float* W1  = (const float*)d_in[5];
    const float* b1  = (const float*)d_in[6];
    const float* W2  = (const float*)d_in[7];
    const float* b2  = (const float*)d_in[8];
    const float* W3  = (const float*)d_in[9];
    const float* b3  = (const float*)d_in[10];
    const float* fcW = (const float*)d_in[11];
    const float* fcb = (const float*)d_in[12];
    const float* l1W = (const float*)d_in[13];
    const float* l1b = (const float*)d_in[14];
    const float* l2W = (const float*)d_in[15];
    const float* l2b = (const float*)d_in[16];
    float* out = (float*)d_out;

    const int bs   = in_sizes[1];                 // 8
    const int E    = in_sizes[2] / 2;
    const int P    = in_sizes[3];
    const int N    = in_sizes[0] / (bs * HID);
    const int HFC  = in_sizes[14];                // 128
    const int NC   = in_sizes[13] / HFC;          // 1000
    const int NCLS = in_sizes[15] / HFC;          // 2
    const int rows = N * bs;

    const int* esrc = eidx;
    const int* edst = eidx + E;

    size_t off = 0;
    auto alloc = [&](size_t bytes) -> void* {
        void* r = (char*)d_ws + off;
        off += (bytes + 255) & ~(size_t)255;
        return r;
    };
    int*   deg    = (int*)  alloc((size_t)N * 4);
    float* dinv   = (float*)alloc((size_t)N * 4);
    int*   rowoff = (int*)  alloc(((size_t)N + 1) * 4);
    int*   fill   = (int*)  alloc((size_t)N * 4);
    int*   ccnt   = (int*)  alloc((size_t)NC * 4);
    int*   coff   = (int*)  alloc(((size_t)NC + 1) * 4);
    int*   cfill  = (int*)  alloc((size_t)NC * 4);
    int*   crow   = (int*)  alloc((size_t)P * 4);
    float* hpoolT = (float*)alloc((size_t)NC * bs * 4);
    float* hpre   = (float*)alloc((size_t)bs * HFC * 4);
    int*   ssrc   = (int*)  alloc((size_t)E * 4);
    float* snorm  = (float*)alloc((size_t)E * 4);
    unsigned int* Yq   = (unsigned int*)alloc((size_t)rows * HID);
    unsigned short* X1 = (unsigned short*)alloc((size_t)rows * HID * 2);
    unsigned short* X2 = (unsigned short*)alloc((size_t)rows * HID * 2);
    float* sArr   = (float*)alloc((size_t)rows * 4);

    // ---- try the single cooperative mega-kernel ----
    MegaArgs ma;
    ma.x = x; ma.esrc = esrc; ma.edst = edst; ma.prow = prow; ma.pcol = pcol;
    ma.W1 = W1; ma.b1 = b1; ma.W2 = W2; ma.b2 = b2; ma.W3 = W3; ma.b3 = b3;
    ma.fcW = fcW; ma.fcb = fcb; ma.l1W = l1W; ma.l1b = l1b; ma.l2W = l2W; ma.l2b = l2b;
    ma.out = out;
    ma.deg = deg; ma.dinv = dinv; ma.rowoff = rowoff; ma.fill = fill;
    ma.ccnt = ccnt; ma.coff = coff; ma.cfill = cfill; ma.crow = crow;
    ma.hpoolT = hpoolT; ma.hpre = hpre;
    ma.ssrc = ssrc; ma.snorm = snorm;
    ma.Yq = Yq; ma.X1 = X1; ma.X2 = X2; ma.sArr = sArr;
    ma.N = N; ma.E = E; ma.P = P; ma.NC = NC; ma.HFC = HFC; ma.NCLS = NCLS;
    ma.rows = rows; ma.bs = bs;

    int maxPerCU = 0;
    hipError_t qe = hipOccupancyMaxActiveBlocksPerMultiprocessor(&maxPerCU, k_mega, 256, 0);
    if (qe == hipSuccess && maxPerCU >= 1) {
        int nBlocks = maxPerCU * 256;       // 256 CUs on MI355X
        if (nBlocks > 2048) nBlocks = 2048;
        void* params[] = { (void*)&ma };
        hipError_t le = hipLaunchCooperativeKernel((const void*)k_mega, dim3(nBlocks),
                                                   dim3(256), params, 0, stream);
        if (le == hipSuccess) return;
    }

    // ---- fallback: round-5 multi-kernel path ----
    hipMemsetAsync(fill, 0, (size_t)N * 4, stream);
    hipMemsetAsync(ccnt, 0, (size_t)NC * 4, stream);
    hipMemsetAsync(cfill, 0, (size_t)NC * 4, stream);
    hipMemsetAsync(hpre, 0, (size_t)bs * HFC * 4, stream);

    int gN = (N + 255) / 256;
    int gE = (E + 255) / 256;
    int gP = (P + 255) / 256;

    k_init_deg<<<gN, 256, 0, stream>>>(deg, N);
    k_count<<<gE, 256, 0, stream>>>(edst, deg, E);
    k_dinv<<<gN, 256, 0, stream>>>(deg, dinv, N);
    k_scan<1><<<1, 256, 0, stream>>>(deg, rowoff, N);
    k_scatter_edges<<<gE, 256, 0, stream>>>(esrc, edst, dinv, rowoff, fill, ssrc, snorm, E);

    k_count<<<gP, 256, 0, stream>>>(pcol, ccnt, P);
    k_scan<0><<<1, 256, 0, stream>>>(ccnt, coff, NC);
    k_scatter_cols<<<gP, 256, 0, stream>>>(prow, pcol, coff, cfill, crow, P);

    const float S1 = 1.f,  iS1 = 1.f;
    const float S2 = 16.f, iS2 = 1.f / 16.f;
    const float S3 = 128.f, iS3 = 1.f / 128.f;

    int gG = (rows + 63) / 64;
    int gA = (N + 3) / 4;
    k_gemm_rt<0><<<gG, 256, 0, stream>>>(x, W1, Yq, S1, N, rows);
    k_agg<0, true><<<gA, 256, 0, stream>>>((const uint2*)Yq, rowoff, ssrc, snorm, dinv, b1, fcW, (uint4*)X1, sArr, iS1, N);
    k_gemm_rt<1><<<gG, 256, 0, stream>>>(X1, W2, Yq, S2, N, rows);
    k_agg<1, true><<<gA, 256, 0, stream>>>((const uint2*)Yq, rowoff, ssrc, snorm, dinv, b2, fcW, (uint4*)X2, sArr, iS2, N);
    k_gemm_rt<1><<<gG, 256, 0, stream>>>(X2, W3, Yq, S3, N, rows);
    k_agg<2, false><<<gA, 256, 0, stream>>>((const uint2*)Yq, rowoff, ssrc, snorm, dinv, b3, fcW, nullptr, sArr, iS3, N);

    k_poolg<<<NC, 64, 0, stream>>>(sArr, coff, crow, hpoolT);

    const int CHUNK = 40;
    dim3 gL1((NC + CHUNK - 1) / CHUNK, bs);
    k_l1p<<<gL1, 128, 0, stream>>>(hpoolT, fcb, l1W, hpre, NC, HFC, CHUNK);
    k_final<<<1, 256, 0, stream>>>(hpre, l1b, l2W, l2b, out, bs, HFC, NCLS);
}

// Round 7
// 377.282 us; speedup vs baseline: 2.8909x; 2.8909x over previous
//
#include <hip/hip_runtime.h>
#include <hip/hip_bf16.h>
#include <hip/hip_fp16.h>
#include <math.h>

#define HID 64

#if defined(__has_builtin)
#if __has_builtin(__builtin_amdgcn_cvt_pk_f32_fp8) && __has_builtin(__builtin_amdgcn_cvt_pk_fp8_f32)
#define HWFP8 1
#endif
#endif

typedef float vfloat2 __attribute__((ext_vector_type(2)));

// ---------------- helpers ----------------

__device__ __forceinline__ unsigned short f2bf(float x) {
    unsigned int u = __float_as_uint(x);
    unsigned int r = u + 0x7fffu + ((u >> 16) & 1u);   // RNE
    return (unsigned short)(r >> 16);
}

#ifndef HWFP8
__device__ __forceinline__ unsigned int enc8_sw(float a) {
    unsigned short hb = __half_as_ushort(__float2half(a));
    unsigned int r = (unsigned int)hb + 0x7fu + ((hb >> 8) & 1u);
    return (r >> 8) & 0xffu;
}
__device__ __forceinline__ float dec8_sw(unsigned int b) {
    return __half2float(__ushort_as_half((unsigned short)(b << 8)));
}
#endif

__device__ __forceinline__ unsigned int enc4(float a, float b, float c, float d) {
#ifdef HWFP8
    int r = __builtin_amdgcn_cvt_pk_fp8_f32(a, b, 0, false);
    r = __builtin_amdgcn_cvt_pk_fp8_f32(c, d, r, true);
    return (unsigned int)r;
#else
    return enc8_sw(a) | (enc8_sw(b) << 8) | (enc8_sw(c) << 16) | (enc8_sw(d) << 24);
#endif
}

__device__ __forceinline__ void dec4(unsigned int w, float* f) {
#ifdef HWFP8
    vfloat2 a = __builtin_amdgcn_cvt_pk_f32_fp8((int)w, false);
    vfloat2 b = __builtin_amdgcn_cvt_pk_f32_fp8((int)w, true);
    f[0] = a.x; f[1] = a.y; f[2] = b.x; f[3] = b.y;
#else
    f[0] = dec8_sw(w & 0xffu); f[1] = dec8_sw((w >> 8) & 0xffu);
    f[2] = dec8_sw((w >> 16) & 0xffu); f[3] = dec8_sw(w >> 24);
#endif
}

__device__ __forceinline__ void dec8(uint2 g, float* f) {
    dec4(g.x, f);
    dec4(g.y, f + 4);
}

// ---------------- fused graph preprocessing (3 kernels, no grid sync) ----------------

// grid-stride: edge in-degree counts AND pathway column counts
__global__ __launch_bounds__(256) void k_pre_count(const int* __restrict__ edst, int* __restrict__ deg, int E,
                                                   const int* __restrict__ pcol, int* __restrict__ ccnt, int P) {
    int gth = blockIdx.x * blockDim.x + threadIdx.x;
    int GT = gridDim.x * blockDim.x;
    for (int e = gth; e < E; e += GT) atomicAdd(&deg[edst[e]], 1);
    for (int p = gth; p < P; p += GT) atomicAdd(&ccnt[pcol[p]], 1);
}

// block 0: exclusive scan deg->rowoff (N); block 1: exclusive scan ccnt->coff (NC);
// all blocks: dinv = rsqrt(deg+1)  (self-loop folded in here)
__global__ __launch_bounds__(256) void k_pre_scan(const int* __restrict__ deg, int* __restrict__ rowoff, int N,
                                                  const int* __restrict__ ccnt, int* __restrict__ coff, int NC,
                                                  float* __restrict__ dinv) {
    __shared__ int part[256];
    int t = threadIdx.x;
    int gth = blockIdx.x * blockDim.x + t;
    int GT = gridDim.x * blockDim.x;
    for (int i = gth; i < N; i += GT) dinv[i] = rsqrtf((float)(deg[i] + 1));

    const int* cnt = nullptr; int* off = nullptr; int n = 0;
    if (blockIdx.x == 0)      { cnt = deg;  off = rowoff; n = N; }
    else if (blockIdx.x == 1) { cnt = ccnt; off = coff;   n = NC; }
    else return;

    int CH = (n + 255) >> 8;
    int lo = min(t * CH, n), hi = min(lo + CH, n);
    int sum = 0;
    for (int i = lo; i < hi; ++i) sum += cnt[i];
    part[t] = sum;
    __syncthreads();
    for (int o = 1; o < 256; o <<= 1) {
        int v = (t >= o) ? part[t - o] : 0;
        __syncthreads();
        part[t] += v;
        __syncthreads();
    }
    int run = (t == 0) ? 0 : part[t - 1];
    for (int i = lo; i < hi; ++i) { off[i] = run; run += cnt[i]; }
    if (t == 255) off[n] = run;
}

// grid-stride: scatter dst-sorted edge CSR AND column CSR
__global__ __launch_bounds__(256) void k_pre_scatter(const int* __restrict__ esrc, const int* __restrict__ edst,
                                                     const float* __restrict__ dinv, const int* __restrict__ rowoff,
                                                     int* __restrict__ fill, int* __restrict__ ssrc,
                                                     float* __restrict__ snorm, int E,
                                                     const int* __restrict__ prow, const int* __restrict__ pcol,
                                                     const int* __restrict__ coff, int* __restrict__ cfill,
                                                     int* __restrict__ crow, int P) {
    int gth = blockIdx.x * blockDim.x + threadIdx.x;
    int GT = gridDim.x * blockDim.x;
    for (int e = gth; e < E; e += GT) {
        int s = esrc[e], d = edst[e];
        int pos = rowoff[d] + atomicAdd(&fill[d], 1);
        ssrc[pos]  = s;
        snorm[pos] = dinv[s] * dinv[d];
    }
    for (int p = gth; p < P; p += GT) {
        int c = pcol[p];
        int pos = coff[c] + atomicAdd(&cfill[c], 1);
        crow[pos] = prow[p];
    }
}

// ---------------- GCN layer ----------------

// Register-tiled GEMM: Y[row, h] = (sum_k X[row, k] * W[k, h]) * S, Y stored fp8.
// MODE 0: X = fp32, layout [b, n, k] with row = n*bs+b (bs==8). MODE 1: X = bf16, [row, k].
template<int MODE>
__global__ __launch_bounds__(256) void k_gemm_rt(const void* __restrict__ Xv,
                                                 const float* __restrict__ W,
                                                 unsigned int* __restrict__ Yq,
                                                 float S, int N, int rowsTot) {
    __shared__ float sW[64 * 64];
    __shared__ float sXT[64 * 68];
    int t = threadIdx.x;
    int r0 = blockIdx.x * 64;

#pragma unroll
    for (int i = 0; i < 16; ++i) sW[t + i * 256] = W[t + i * 256];

    {
        int row = t & 63;
        int kg = t >> 6;
        int gr = r0 + row;
        bool ok = gr < rowsTot;
        const float* Xf = (const float*)Xv;
        const unsigned short* Xh = (const unsigned short*)Xv;
#pragma unroll
        for (int i = 0; i < 4; ++i) {
            int k = (kg + i * 4) * 4;
            float4 v = make_float4(0.f, 0.f, 0.f, 0.f);
            if (ok) {
                if (MODE == 0) {
                    int n = gr >> 3, b = gr & 7;
                    v = *(const float4*)&Xf[((size_t)b * N + n) * 64 + k];
                } else {
                    ushort4 u = *(const ushort4*)&Xh[(size_t)gr * 64 + k];
                    v.x = __uint_as_float(((unsigned int)u.x) << 16);
                    v.y = __uint_as_float(((unsigned int)u.y) << 16);
                    v.z = __uint_as_float(((unsigned int)u.z) << 16);
                    v.w = __uint_as_float(((unsigned int)u.w) << 16);
                }
            }
            sXT[(k + 0) * 68 + row] = v.x;
            sXT[(k + 1) * 68 + row] = v.y;
            sXT[(k + 2) * 68 + row] = v.z;
            sXT[(k + 3) * 68 + row] = v.w;
        }
    }
    __syncthreads();

    int ci = t & 15, ri = t >> 4;
    float acc[4][4] = {};
#pragma unroll 16
    for (int k = 0; k < 64; ++k) {
        float4 xr = *(const float4*)&sXT[k * 68 + ri * 4];
        float4 wc = *(const float4*)&sW[k * 64 + ci * 4];
        acc[0][0] = fmaf(xr.x, wc.x, acc[0][0]); acc[0][1] = fmaf(xr.x, wc.y, acc[0][1]);
        acc[0][2] = fmaf(xr.x, wc.z, acc[0][2]); acc[0][3] = fmaf(xr.x, wc.w, acc[0][3]);
        acc[1][0] = fmaf(xr.y, wc.x, acc[1][0]); acc[1][1] = fmaf(xr.y, wc.y, acc[1][1]);
        acc[1][2] = fmaf(xr.y, wc.z, acc[1][2]); acc[1][3] = fmaf(xr.y, wc.w, acc[1][3]);
        acc[2][0] = fmaf(xr.z, wc.x, acc[2][0]); acc[2][1] = fmaf(xr.z, wc.y, acc[2][1]);
        acc[2][2] = fmaf(xr.z, wc.z, acc[2][2]); acc[2][3] = fmaf(xr.z, wc.w, acc[2][3]);
        acc[3][0] = fmaf(xr.w, wc.x, acc[3][0]); acc[3][1] = fmaf(xr.w, wc.y, acc[3][1]);
        acc[3][2] = fmaf(xr.w, wc.z, acc[3][2]); acc[3][3] = fmaf(xr.w, wc.w, acc[3][3]);
    }

#pragma unroll
    for (int j = 0; j < 4; ++j) {
        int row = r0 + ri * 4 + j;
        if (row < rowsTot)
            Yq[(size_t)row * 16 + ci] =
                enc4(acc[j][0] * S, acc[j][1] * S, acc[j][2] * S, acc[j][3] * S);
    }
}

// 4 nodes per 256-thread block, one wave per node; fp8 messages; 8-deep edge pipeline.
template<int LAYER, bool STORE>
__global__ __launch_bounds__(256) void k_agg(const uint2* __restrict__ Y,
                                             const int* __restrict__ rowoff,
                                             const int* __restrict__ ssrc,
                                             const float* __restrict__ snorm,
                                             const float* __restrict__ dinv,
                                             const float* __restrict__ bias,
                                             const float* __restrict__ fcW,
                                             uint4* __restrict__ O,
                                             float* __restrict__ sArr,
                                             float invS, int N) {
    int n = blockIdx.x * 4 + (threadIdx.x >> 6);
    if (n >= N) return;
    int lane = threadIdx.x & 63;
    int hb = (lane & 7) * 8;
    float bv[8], wv[8];
#pragma unroll
    for (int k = 0; k < 8; ++k) { bv[k] = bias[hb + k]; wv[k] = fcW[3 * (hb + k) + LAYER]; }

    float dn = dinv[n];
    float w0 = dn * dn;
    float acc[8], f[8];
    dec8(Y[(size_t)n * 64 + lane], f);
#pragma unroll
    for (int k = 0; k < 8; ++k) acc[k] = w0 * f[k];

    int beg = rowoff[n], end = rowoff[n + 1];
    int i = beg;
    for (; i + 7 < end; i += 8) {
        int   sI[8];
        float wI[8];
        uint2 g[8];
#pragma unroll
        for (int u = 0; u < 8; ++u) { sI[u] = ssrc[i + u]; wI[u] = snorm[i + u]; }
#pragma unroll
        for (int u = 0; u < 8; ++u) g[u] = Y[(size_t)sI[u] * 64 + lane];
#pragma unroll
        for (int u = 0; u < 8; ++u) {
            dec8(g[u], f);
#pragma unroll
            for (int k = 0; k < 8; ++k) acc[k] = fmaf(wI[u], f[k], acc[k]);
        }
    }
    for (; i < end; ++i) {
        int s = ssrc[i];
        float w = snorm[i];
        dec8(Y[(size_t)s * 64 + lane], f);
#pragma unroll
        for (int k = 0; k < 8; ++k) acc[k] = fmaf(w, f[k], acc[k]);
    }

    float sv = 0.f;
#pragma unroll
    for (int k = 0; k < 8; ++k) {
        float o = fmaxf(fmaf(acc[k], invS, bv[k]), 0.f);
        acc[k] = o;
        sv = fmaf(o, wv[k], sv);
    }
    if (STORE) {
        uint4 o;
        o.x = (unsigned int)f2bf(acc[0]) | ((unsigned int)f2bf(acc[1]) << 16);
        o.y = (unsigned int)f2bf(acc[2]) | ((unsigned int)f2bf(acc[3]) << 16);
        o.z = (unsigned int)f2bf(acc[4]) | ((unsigned int)f2bf(acc[5]) << 16);
        o.w = (unsigned int)f2bf(acc[6]) | ((unsigned int)f2bf(acc[7]) << 16);
        O[(size_t)n * 64 + lane] = o;
    }
    sv += __shfl_down(sv, 4, 64);
    sv += __shfl_down(sv, 2, 64);
    sv += __shfl_down(sv, 1, 64);
    if ((lane & 7) == 0) {
        int b = lane >> 3;
        float* sp = sArr + (size_t)n * 8 + b;
        if (LAYER == 0) *sp = sv;
        else            *sp += sv;
    }
}

// ---------------- pooling head ----------------

__global__ __launch_bounds__(64) void k_poolg(const float* __restrict__ sArr,
                                              const int* __restrict__ coff,
                                              const int* __restrict__ crow,
                                              float* __restrict__ hpoolT) {
    int c = blockIdx.x;
    int lane = threadIdx.x;
    int beg = coff[c], end = coff[c + 1];
    int b = lane & 7;
    float acc = 0.f;
    for (int i = beg + (lane >> 3); i < end; i += 8) {
        int r = crow[i];
        acc += sArr[(size_t)r * 8 + b];
    }
    acc += __shfl_down(acc, 32, 64);
    acc += __shfl_down(acc, 16, 64);
    acc += __shfl_down(acc, 8, 64);
    if (lane < 8) {
        float inv = 1.f / fmaxf((float)(end - beg), 1.f);
        hpoolT[(size_t)c * 8 + b] = acc * inv;
    }
}

__global__ __launch_bounds__(128) void k_l1p(const float* __restrict__ hpoolT,
                                             const float* __restrict__ fcb,
                                             const float* __restrict__ l1W,
                                             float* __restrict__ hpre,
                                             int NC, int HFC, int CHUNK) {
    __shared__ float hl[64];
    int b = blockIdx.y;
    int c0 = blockIdx.x * CHUNK;
    int j = threadIdx.x;
    int cend = min(c0 + CHUNK, NC);
    for (int c = c0 + j; c < cend; c += blockDim.x)
        hl[c - c0] = hpoolT[(size_t)c * 8 + b] + fcb[0];
    __syncthreads();
    float acc = 0.f;
    for (int c = c0; c < cend; ++c) acc = fmaf(hl[c - c0], l1W[(size_t)c * HFC + j], acc);
    atomicAdd(&hpre[(size_t)b * HFC + j], acc);
}

__global__ __launch_bounds__(256) void k_final(const float* __restrict__ hpre,
                                               const float* __restrict__ l1b,
                                               const float* __restrict__ l2W,
                                               const float* __restrict__ l2b,
                                               float* __restrict__ out,
                                               int bs, int HFC, int NCLS) {
    __shared__ float z[64];
    int t = threadIdx.x;
    int g = t >> 4, l16 = t & 15;
    int nout = bs * NCLS;
    float v = 0.f;
    int b = g / NCLS, k = g - b * NCLS;
    if (g < nout) {
        for (int j = l16; j < HFC; j += 16) {
            float h = fmaxf(hpre[(size_t)b * HFC + j] + l1b[j], 0.f);
            v = fmaf(h, l2W[(size_t)j * NCLS + k], v);
        }
    }
    v += __shfl_down(v, 8, 64);
    v += __shfl_down(v, 4, 64);
    v += __shfl_down(v, 2, 64);
    v += __shfl_down(v, 1, 64);
    if (l16 == 0 && g < nout) z[g] = v + l2b[k];
    __syncthreads();
    if (t < bs) {
        float m = -1e30f;
        for (int c = 0; c < NCLS; ++c) m = fmaxf(m, z[t * NCLS + c]);
        float s = 0.f;
        for (int c = 0; c < NCLS; ++c) s += expf(z[t * NCLS + c] - m);
        float lse = m + logf(s);
        for (int c = 0; c < NCLS; ++c) out[t * NCLS + c] = z[t * NCLS + c] - lse;
    }
}

// ---------------- launcher ----------------

extern "C" void kernel_launch(void* const* d_in, const int* in_sizes, int n_in,
                              void* d_out, int out_size, void* d_ws, size_t ws_size,
                              hipStream_t stream) {
    const float* x   = (const float*)d_in[0];
    const int* eidx  = (const int*)d_in[2];
    const int* prow  = (const int*)d_in[3];
    const int* pcol  = (const int*)d_in[4];
    const float* W1  = (const float*)d_in[5];
    const float* b1  = (const float*)d_in[6];
    const float* W2  = (const float*)d_in[7];
    const float* b2  = (const float*)d_in[8];
    const float* W3  = (const float*)d_in[9];
    const float* b3  = (const float*)d_in[10];
    const float* fcW = (const float*)d_in[11];
    const float* fcb = (const float*)d_in[12];
    const float* l1W = (const float*)d_in[13];
    const float* l1b = (const float*)d_in[14];
    const float* l2W = (const float*)d_in[15];
    const float* l2b = (const float*)d_in[16];
    float* out = (float*)d_out;

    const int bs   = in_sizes[1];                 // 8
    const int E    = in_sizes[2] / 2;
    const int P    = in_sizes[3];
    const int N    = in_sizes[0] / (bs * HID);
    const int HFC  = in_sizes[14];                // 128
    const int NC   = in_sizes[13] / HFC;          // 1000
    const int NCLS = in_sizes[15] / HFC;          // 2
    const int rows = N * bs;

    const int* esrc = eidx;
    const int* edst = eidx + E;

    size_t off = 0;
    auto alloc = [&](size_t bytes) -> void* {
        void* r = (char*)d_ws + off;
        off += (bytes + 255) & ~(size_t)255;
        return r;
    };
    // ---- zero region (one memset covers all of these, padding included) ----
    char* zbase   = (char*)d_ws;
    int*   deg    = (int*)  alloc((size_t)N * 4);
    int*   fill   = (int*)  alloc((size_t)N * 4);
    int*   ccnt   = (int*)  alloc((size_t)NC * 4);
    int*   cfill  = (int*)  alloc((size_t)NC * 4);
    float* hpre   = (float*)alloc((size_t)bs * HFC * 4);
    size_t zspan  = off;
    // ---- rest ----
    float* dinv   = (float*)alloc((size_t)N * 4);
    int*   rowoff = (int*)  alloc(((size_t)N + 1) * 4);
    int*   coff   = (int*)  alloc(((size_t)NC + 1) * 4);
    int*   crow   = (int*)  alloc((size_t)P * 4);
    float* hpoolT = (float*)alloc((size_t)NC * bs * 4);
    int*   ssrc   = (int*)  alloc((size_t)E * 4);
    float* snorm  = (float*)alloc((size_t)E * 4);
    unsigned int* Yq   = (unsigned int*)alloc((size_t)rows * HID);
    unsigned short* X1 = (unsigned short*)alloc((size_t)rows * HID * 2);
    unsigned short* X2 = (unsigned short*)alloc((size_t)rows * HID * 2);
    float* sArr   = (float*)alloc((size_t)rows * 4);

    hipMemsetAsync(zbase, 0, zspan, stream);

    // preprocessing: 3 fused kernels
    int gPre = 512;
    k_pre_count<<<gPre, 256, 0, stream>>>(edst, deg, E, pcol, ccnt, P);
    k_pre_scan<<<64, 256, 0, stream>>>(deg, rowoff, N, ccnt, coff, NC, dinv);
    k_pre_scatter<<<gPre, 256, 0, stream>>>(esrc, edst, dinv, rowoff, fill, ssrc, snorm, E,
                                            prow, pcol, coff, cfill, crow, P);

    const float S1 = 1.f,  iS1 = 1.f;
    const float S2 = 16.f, iS2 = 1.f / 16.f;
    const float S3 = 128.f, iS3 = 1.f / 128.f;

    int gG = (rows + 63) / 64;
    int gA = (N + 3) / 4;
    k_gemm_rt<0><<<gG, 256, 0, stream>>>(x, W1, Yq, S1, N, rows);
    k_agg<0, true><<<gA, 256, 0, stream>>>((const uint2*)Yq, rowoff, ssrc, snorm, dinv, b1, fcW, (uint4*)X1, sArr, iS1, N);
    k_gemm_rt<1><<<gG, 256, 0, stream>>>(X1, W2, Yq, S2, N, rows);
    k_agg<1, true><<<gA, 256, 0, stream>>>((const uint2*)Yq, rowoff, ssrc, snorm, dinv, b2, fcW, (uint4*)X2, sArr, iS2, N);
    k_gemm_rt<1><<<gG, 256, 0, stream>>>(X2, W3, Yq, S3, N, rows);
    k_agg<2, false><<<gA, 256, 0, stream>>>((const uint2*)Yq, rowoff, ssrc, snorm, dinv, b3, fcW, nullptr, sArr, iS3, N);

    k_poolg<<<NC, 64, 0, stream>>>(sArr, coff, crow, hpoolT);

    const int CHUNK = 40;
    dim3 gL1((NC + CHUNK - 1) / CHUNK, bs);
    k_l1p<<<gL1, 128, 0, stream>>>(hpoolT, fcb, l1W, hpre, NC, HFC, CHUNK);
    k_final<<<1, 256, 0, stream>>>(hpre, l1b, l2W, l2b, out, bs, HFC, NCLS);
}